// Round 17
// baseline (277.667 us; speedup 1.0000x reference)
//
#include <hip/hip_runtime.h>

typedef _Float16 f16x8 __attribute__((ext_vector_type(8)));
typedef _Float16 f16x4 __attribute__((ext_vector_type(4)));
typedef float    f32x4 __attribute__((ext_vector_type(4)));
typedef unsigned int u32x4 __attribute__((ext_vector_type(4)));   // NT-store legal

typedef const __attribute__((address_space(1))) void gvoid_t;
typedef __attribute__((address_space(3))) void lvoid_t;

// LDS-visibility-only barrier (no vmcnt drain): DMA/prefetch loads and NT
// stores stay in flight across it.
__device__ __forceinline__ void lds_barrier() {
    asm volatile("s_waitcnt lgkmcnt(0)" ::: "memory");
    __builtin_amdgcn_sched_barrier(0);
    __builtin_amdgcn_s_barrier();
    __builtin_amdgcn_sched_barrier(0);
}

// ===========================================================================
// K1: QKV 1x1-conv projection. UNCHANGED from R13 (timed ~43us, at the NT
// write-path roofline): MFMA -> OUT LDS transpose -> NT 1KB bulk stores.
// ===========================================================================
#define W_OFF   0      // 24576 B : w [192o][64c] fp16, row 128B, swz (orow&7)<<4
#define XA_OFF  24576  // 16384 B : x tile buf A fp16 [64c][128px], swz ((c>>3)&7)<<4
#define XB_OFF  40960  // 16384 B : x tile buf B
#define OUT_OFF 57344  // 24576 B : out [96oo][128px] fp16, swz (oo&7)<<4

__global__ __launch_bounds__(256, 2) void proj_qkv_mfma(
    const float* __restrict__ x,
    const float* __restrict__ wq, const float* __restrict__ bq,
    const float* __restrict__ wk, const float* __restrict__ bk,
    const float* __restrict__ wv, const float* __restrict__ bv,
    _Float16* __restrict__ Qh, _Float16* __restrict__ Kh, _Float16* __restrict__ Vh,
    const int rstride)
{
    __shared__ __align__(16) unsigned char lds[81920];

    const int tid  = threadIdx.x;
    const int lane = tid & 63;
    const int wid  = tid >> 6;
    const int q4   = lane >> 4;
    const int l15  = lane & 15;

    const int pg0  = blockIdx.x << 10;        // 1024 px per block
    const int bb   = pg0 >> 16;               // batch (1024 divides 65536)
    const int pix0 = pg0 & 65535;
    const float* xb = x + ((size_t)bb << 22); // bb*64*65536 (x stride fixed)

    const int sc = tid >> 5;                  // c row base for staging
    const int sslot = tid & 31;               // px = sslot*4

    // ---- bias preload ----
    float bld[12];
#pragma unroll
    for (int ot = 0; ot < 12; ++ot) {
        const int mat = ot >> 2;
        const float* bs = (mat == 0) ? bq : (mat == 1) ? bk : bv;
        bld[ot] = bs[((ot & 3) << 4) + l15];
    }

    // ---- stage ALL weights once: [192][64] f32 -> fp16 LDS ----
#pragma unroll
    for (int it = 0; it < 12; ++it) {
        const int idx  = (it << 8) + tid;
        const int orow = idx >> 4;
        const int s    = idx & 15;
        const int mat  = orow >> 6;
        const float* wsrc = (mat == 0) ? wq : (mat == 1) ? wk : wv;
        const f32x4 v = *(const f32x4*)(wsrc + ((orow & 63) << 6) + (s << 2));
        f16x4 h;
#pragma unroll
        for (int j = 0; j < 4; ++j) h[j] = (_Float16)v[j];
        const int a = ((orow << 7) + (s << 3)) ^ ((orow & 7) << 4);
        *(f16x4*)(lds + W_OFF + a) = h;
    }

    // ---- prologue: stage tile 0 into buf A ----
    {
        f32x4 xv[8];
#pragma unroll
        for (int it = 0; it < 8; ++it) {
            const int c = (it << 3) + sc;
            xv[it] = *(const f32x4*)(xb + ((size_t)c << 16) + pix0 + (sslot << 2));
        }
#pragma unroll
        for (int it = 0; it < 8; ++it) {
            const int c = (it << 3) + sc;
            f16x4 h;
#pragma unroll
            for (int j = 0; j < 4; ++j) h[j] = (_Float16)xv[it][j];
            const int a = ((c << 8) + (sslot << 3)) ^ (((c >> 3) & 7) << 4);
            *(f16x4*)(lds + XA_OFF + a) = h;
        }
    }
    __syncthreads();

    const int wpx = wid << 5;                  // wave px base (32 px/wave)

    for (int t = 0; t < 8; ++t) {
        const int bufo = (t & 1) ? XB_OFF : XA_OFF;
        const int nbufo = (t & 1) ? XA_OFF : XB_OFF;
        const int pixT = pix0 + (t << 7);

        // ---- issue tile t+1 loads NOW (in flight during compute) ----
        f32x4 xv[8];
        if (t < 7) {
            const int pixN = pixT + 128;
#pragma unroll
            for (int it = 0; it < 8; ++it) {
                const int c = (it << 3) + sc;
                xv[it] = *(const f32x4*)(xb + ((size_t)c << 16) + pixN + (sslot << 2));
            }
        }

        // ---- A fragments: lane l15 = px, k = c ----
        f16x8 af[2][2];
#pragma unroll
        for (int pt = 0; pt < 2; ++pt)
#pragma unroll
            for (int kc = 0; kc < 2; ++kc) {
                const int px = wpx + (pt << 4) + l15;
                f16x8 a;
#pragma unroll
                for (int j = 0; j < 8; ++j) {
                    const int c  = (kc << 5) + (q4 << 3) + j;
                    const int ad = ((c << 8) + (px << 1)) ^ (((c >> 3) & 7) << 4);
                    a[j] = *(const _Float16*)(lds + bufo + ad);
                }
                af[pt][kc] = a;
            }

        // ---- 2 rounds x 6 o-tiles: MFMA -> OUT LDS -> coalesced NT store ----
#pragma unroll
        for (int rd = 0; rd < 2; ++rd) {
            if (rd) lds_barrier();
#pragma unroll
            for (int ot6 = 0; ot6 < 6; ++ot6) {
                const int ot  = rd * 6 + ot6;
                const int row = (ot << 4) + l15;
                const int rsw = (row & 7) << 4;
                const f16x8 bf0 = *(const f16x8*)(lds + W_OFF + (((row << 7) + (q4 << 4)) ^ rsw));
                const f16x8 bf1 = *(const f16x8*)(lds + W_OFF + (((row << 7) + 64 + (q4 << 4)) ^ rsw));
                const int oo  = (ot6 << 4) + l15;
                const int osw = (oo & 7) << 4;
#pragma unroll
                for (int pt = 0; pt < 2; ++pt) {
                    f32x4 acc = { bld[ot], bld[ot], bld[ot], bld[ot] };
                    acc = __builtin_amdgcn_mfma_f32_16x16x32_f16(af[pt][0], bf0, acc, 0, 0, 0);
                    acc = __builtin_amdgcn_mfma_f32_16x16x32_f16(af[pt][1], bf1, acc, 0, 0, 0);
                    f16x4 h;
#pragma unroll
                    for (int r = 0; r < 4; ++r) h[r] = (_Float16)acc[r];
                    const int px = wpx + (pt << 4) + (q4 << 2);
                    *(f16x4*)(lds + OUT_OFF + (((oo << 8) + (px << 1)) ^ osw)) = h;
                }
            }
            lds_barrier();

            // bulk store: 4 rows x 256B contiguous per wave instr, NT flag
#pragma unroll
            for (int it = 0; it < 6; ++it) {
                const int idx = (it << 8) + tid;
                const int oo  = idx >> 4;          // 0..95
                const int sl  = idx & 15;          // 16B slot (8 px)
                const u32x4 vst = *(const u32x4*)(lds + OUT_OFF +
                    (((oo << 8) + (sl << 4)) ^ ((oo & 7) << 4)));
                const int ot  = rd * 6 + (oo >> 4);
                const int mat = ot >> 2;
                _Float16* ob = (mat == 0) ? Qh : (mat == 1) ? Kh : Vh;
                const int orow = ((ot & 3) << 4) + (oo & 15);
                u32x4* dst = (u32x4*)(ob + (size_t)((bb << 6) + orow) * rstride + pixT + (sl << 3));
                __builtin_nontemporal_store(vst, dst);
            }
        }

        // ---- cvt + ds_write tile t+1 into other x buffer ----
        if (t < 7) {
#pragma unroll
            for (int it = 0; it < 8; ++it) {
                const int c = (it << 3) + sc;
                f16x4 h;
#pragma unroll
                for (int j = 0; j < 4; ++j) h[j] = (_Float16)xv[it][j];
                const int a = ((c << 8) + (sslot << 3)) ^ (((c >> 3) & 7) << 4);
                *(f16x4*)(lds + nbufo + a) = h;
            }
        }
        lds_barrier();
    }
}

// ===========================================================================
// K2: fused attention, persistent (grid 256, 2 (b,c)/block) with cross-
// iteration pipelining. Round-17 change: __launch_bounds__(1024,4) -> (1024,1).
// R16's regression was pure VGPR spill (FETCH +98MB / WRITE +183MB scratch
// traffic at the forced 64-VGPR cap); LDS=160KB pins occupancy at 1 block/CU
// regardless, so the cap bought nothing. Structure unchanged from R16:
// after PV, next slice's Q/K chunks 0,1 DMA into the dead P region; the
// epilogue (VT staging) runs while those loads + NT-store drain proceed in
// background. Position-exact counted vmcnts (audited: dma0/dma1 are older
// than epilogue stores, so vmcnt(20) retires DMA without waiting on stores).
// ===========================================================================
#define P_OFF  0        // phase3: P fp16 [256][512B] | phase1: DMA bufs 0/65536
#define RED_OFF 131072  //  4096 B : softmax partials (phase 2 only)
#define VT_OFF 131072   // 32768 B : Vt fp16 (phase 3) | epilogue staging

__global__ __launch_bounds__(1024, 1) void attn_rowsm(
    const _Float16* __restrict__ Qh, const _Float16* __restrict__ Kh,
    const _Float16* __restrict__ Vh, const float* __restrict__ gamma,
    float* __restrict__ out, const int rstride)
{
    __shared__ __align__(16) unsigned char lds[163840];

    const int tid  = threadIdx.x;
    const int lane = tid & 63;
    const int wid  = tid >> 6;
    const int wr   = wid >> 2;
    const int wc   = wid & 3;
    const int q4   = lane >> 4;
    const int l15  = lane & 15;

    // DMA one 64-col chunk of Q and K (4 instrs/wave, 64KB/block total)
    auto dma_chunk = [&](size_t qb, int buf, int c) {
#pragma unroll
        for (int i = 0; i < 2; ++i) {
            const int idx = (((wid << 1) + i) << 10);   // wave's 1KB region
            const int h   = (idx >> 7) + (lane >> 3);
            const int sl  = lane & 7;
            const int kin = (sl << 3) ^ ((h & 7) << 3); // pre-swizzled col
            const size_t src = qb + (size_t)h * 256 + c * 64 + kin;
            __builtin_amdgcn_global_load_lds((gvoid_t*)(Qh + src),
                (lvoid_t*)(lds + buf + idx), 16, 0, 0);
            __builtin_amdgcn_global_load_lds((gvoid_t*)(Kh + src),
                (lvoid_t*)(lds + buf + 32768 + idx), 16, 0, 0);
        }
    };

    const float g_sig = 1.0f / (1.0f + __expf(-gamma[0]));

    // prologue: it=0 chunks 0,1 in flight
    dma_chunk((size_t)blockIdx.x * rstride, 0, 0);
    dma_chunk((size_t)blockIdx.x * rstride, 65536, 1);
    __builtin_amdgcn_sched_barrier(0);

#pragma unroll
    for (int it = 0; it < 2; ++it) {
        const size_t qbase = (size_t)(blockIdx.x + (it << 8)) * rstride;

        f32x4 acc[4][4];
        const f32x4 fzero = {0.f, 0.f, 0.f, 0.f};
#pragma unroll
        for (int i = 0; i < 4; ++i)
#pragma unroll
            for (int j = 0; j < 4; ++j) acc[i][j] = fzero;

        // ------------- phase 1: att = Q K^T (chunks 0,1 pre-issued) --------
        auto qk_chunk = [&](int buf) {
#pragma unroll
            for (int sub = 0; sub < 2; ++sub) {
                f16x8 bf[4];
#pragma unroll
                for (int ni = 0; ni < 4; ++ni) {
                    const int g = (wc << 6) + (ni << 4) + l15;
                    bf[ni] = *(const f16x8*)(lds + buf + 32768 + (g << 7) +
                             (((sub << 6) + (q4 << 4)) ^ ((g & 7) << 4)));
                }
#pragma unroll
                for (int mi = 0; mi < 4; ++mi) {
                    const int h = (wr << 6) + (mi << 4) + l15;
                    const f16x8 afr = *(const f16x8*)(lds + buf + (h << 7) +
                             (((sub << 6) + (q4 << 4)) ^ ((h & 7) << 4)));
#pragma unroll
                    for (int ni = 0; ni < 4; ++ni)
                        acc[mi][ni] = __builtin_amdgcn_mfma_f32_16x16x32_f16(afr, bf[ni], acc[mi][ni], 0, 0, 0);
                }
            }
        };

#pragma unroll
        for (int c = 0; c < 4; ++c) {
            const int buf = (c & 1) << 16;
            if (c == 1) dma_chunk(qbase, 0, 2);        // buf0 free after c=0
            if (c == 2) dma_chunk(qbase, 65536, 3);    // buf1 free after c=1
            __builtin_amdgcn_sched_barrier(0);
            // position-exact waits: ops issued after chunk c still in flight
            if (c == 0) { if (it == 0) asm volatile("s_waitcnt vmcnt(4)" ::: "memory");
                          else         asm volatile("s_waitcnt vmcnt(20)" ::: "memory"); }
            if (c == 1) { if (it == 0) asm volatile("s_waitcnt vmcnt(4)" ::: "memory");
                          else         asm volatile("s_waitcnt vmcnt(20)" ::: "memory"); }
            if (c == 2) asm volatile("s_waitcnt vmcnt(4)" ::: "memory");
            if (c == 3) asm volatile("s_waitcnt vmcnt(0)" ::: "memory");
            __builtin_amdgcn_sched_barrier(0);
            lds_barrier();                   // all waves' chunk-c DMA landed
            qk_chunk(buf);
            lds_barrier();                   // reads done before overwrite
        }

        // V chunk-0 prefetch (2 adjacent g-rows/thread), in flight thru softmax
        const int gp = tid >> 5;
        const int wo = tid & 31;
        uint4 vd0 = *(const uint4*)(Vh + qbase + (size_t)(gp << 1) * 256 + wo * 8);
        uint4 vd1 = *(const uint4*)(Vh + qbase + (size_t)((gp << 1) + 1) * 256 + wo * 8);

        // ---------------- phase 2: diag add + softmax over h ----------------
        if (wr == wc) {
            const int rn = l15 - (q4 << 2);
            if (rn >= 0 && rn < 4) {
#pragma unroll
                for (int mi = 0; mi < 4; ++mi) acc[mi][mi][rn] += g_sig;
            }
        }

        float* red = (float*)(lds + RED_OFF);
        float cmx[4], cinv[4];

        lds_barrier();
#pragma unroll
        for (int ni = 0; ni < 4; ++ni) {
            float m = -3.0e38f;
#pragma unroll
            for (int mi = 0; mi < 4; ++mi)
#pragma unroll
                for (int r = 0; r < 4; ++r) m = fmaxf(m, acc[mi][ni][r]);
            m = fmaxf(m, __shfl_xor(m, 16));
            m = fmaxf(m, __shfl_xor(m, 32));
            cmx[ni] = m;
            if (q4 == 0) red[wr * 256 + (wc << 6) + (ni << 4) + l15] = m;
        }
        lds_barrier();
#pragma unroll
        for (int ni = 0; ni < 4; ++ni) {
            const int col = (wc << 6) + (ni << 4) + l15;
            float m = red[col];
            m = fmaxf(m, red[256 + col]);
            m = fmaxf(m, red[512 + col]);
            m = fmaxf(m, red[768 + col]);
            cmx[ni] = m;
        }
        lds_barrier();
#pragma unroll
        for (int ni = 0; ni < 4; ++ni) {
            float s = 0.f;
#pragma unroll
            for (int mi = 0; mi < 4; ++mi)
#pragma unroll
                for (int r = 0; r < 4; ++r) {
                    const float e = __expf(acc[mi][ni][r] - cmx[ni]);
                    acc[mi][ni][r] = e;
                    s += e;
                }
            s += __shfl_xor(s, 16);
            s += __shfl_xor(s, 32);
            if (q4 == 0) red[wr * 256 + (wc << 6) + (ni << 4) + l15] = s;
        }
        lds_barrier();
#pragma unroll
        for (int ni = 0; ni < 4; ++ni) {
            const int col = (wc << 6) + (ni << 4) + l15;
            cinv[ni] = 1.0f / (red[col] + red[256 + col] + red[512 + col] + red[768 + col]);
        }

        // write normalized P to LDS (fp16, conflict-free swz)
#pragma unroll
        for (int mi = 0; mi < 4; ++mi) {
            const int hbase = (wr << 6) + (mi << 4) + (q4 << 2);
#pragma unroll
            for (int r = 0; r < 4; ++r) {
                const int h  = hbase + r;
                const int hb = h << 9;
                const int sw = ((h & 3) << 4) ^ (((h >> 2) & 3) << 5);
#pragma unroll
                for (int ni = 0; ni < 4; ++ni) {
                    const int g = (wc << 6) + (ni << 4) + l15;
                    *(_Float16*)(lds + P_OFF + ((hb + (g << 1)) ^ sw)) =
                        (_Float16)(acc[mi][ni][r] * cinv[ni]);
                }
            }
        }

        // ---------------- phase 3: out = P V (64-g chunks) ----------------
#pragma unroll
        for (int i = 0; i < 4; ++i)
#pragma unroll
            for (int j = 0; j < 4; ++j) acc[i][j] = fzero;

        auto v_scatter = [&](const uint4& a, const uint4& b) {
            const unsigned short* e0 = (const unsigned short*)&a;
            const unsigned short* e1 = (const unsigned short*)&b;
#pragma unroll
            for (int j = 0; j < 8; ++j) {
                const int w  = (wo << 3) + j;
                const int fw = ((w & 7) ^ ((w >> 3) & 7)) << 4;
                const unsigned int pk = (unsigned int)e0[j] | ((unsigned int)e1[j] << 16);
                *(unsigned int*)(lds + VT_OFF + (((w << 7) + (gp << 2)) ^ fw)) = pk;
            }
        };
        auto pv_chunk = [&](int gc) {
#pragma unroll
            for (int sub = 0; sub < 2; ++sub) {
                f16x8 bf[4];
#pragma unroll
                for (int ni = 0; ni < 4; ++ni) {
                    const int w  = (wc << 6) + (ni << 4) + l15;
                    const int fw = ((w & 7) ^ ((w >> 3) & 7)) << 4;
                    bf[ni] = *(const f16x8*)(lds + VT_OFF + (w << 7) +
                             (((sub << 6) + (q4 << 4)) ^ fw));
                }
#pragma unroll
                for (int mi = 0; mi < 4; ++mi) {
                    const int h  = (wr << 6) + (mi << 4) + l15;
                    const int sw = ((h & 3) << 4) ^ (((h >> 2) & 3) << 5);
                    const f16x8 afr = *(const f16x8*)(lds + P_OFF + (h << 9) +
                        ((((gc + (sub << 5) + (q4 << 3)) << 1)) ^ sw));
#pragma unroll
                    for (int ni = 0; ni < 4; ++ni)
                        acc[mi][ni] = __builtin_amdgcn_mfma_f32_16x16x32_f16(afr, bf[ni], acc[mi][ni], 0, 0, 0);
                }
            }
        };

        for (int gc = 0; gc < 256; gc += 64) {
            lds_barrier();
            v_scatter(vd0, vd1);
            if (gc < 192) {
                const size_t vgn = qbase + (size_t)(gc + 64 + (gp << 1)) * 256 + wo * 8;
                vd0 = *(const uint4*)(Vh + vgn);
                vd1 = *(const uint4*)(Vh + vgn + 256);
            }
            lds_barrier();
            pv_chunk(gc);
        }

        lds_barrier();                       // all P/VT reads done
        // ---- cross-iteration pipeline: next slice's chunk 0,1 DMA ----
        if (it == 0) {
            const size_t qb2 = (size_t)(blockIdx.x + 256) * rstride;
            dma_chunk(qb2, 0, 0);            // P region dead -> buf0
            dma_chunk(qb2, 65536, 1);        // -> buf1
            __builtin_amdgcn_sched_barrier(0);
        }

        // ---- epilogue: 8 passes x 32 rows via VT staging + NT bulk store ----
        float* op = out + ((size_t)(blockIdx.x + (it << 8)) << 16);
#pragma unroll
        for (int pass = 0; pass < 8; ++pass) {
            lds_barrier();
            if (wr == (pass >> 1)) {         // wave-uniform: 4 waves stage
#pragma unroll
                for (int mi2 = 0; mi2 < 2; ++mi2) {
                    const int mi = ((pass & 1) << 1) + mi2;
#pragma unroll
                    for (int r = 0; r < 4; ++r) {
                        const int lr = (mi2 << 4) + (q4 << 2) + r;   // 0..31
                        const int sw = (lr & 7) << 4;
#pragma unroll
                        for (int ni = 0; ni < 4; ++ni) {
                            const int w = (wc << 6) + (ni << 4) + l15;
                            *(float*)(lds + VT_OFF + (((lr << 10) + (w << 2)) ^ sw)) =
                                acc[mi][ni][r];
                        }
                    }
                }
            }
            lds_barrier();
#pragma unroll
            for (int it2 = 0; it2 < 2; ++it2) {
                const int idx = (it2 << 10) + tid;
                const int row = idx >> 6;    // 0..31
                const int sl  = idx & 63;
                const u32x4 v = *(const u32x4*)(lds + VT_OFF +
                    (((row << 10) + (sl << 4)) ^ ((row & 7) << 4)));
                const int h = (pass << 5) + row;
                __builtin_nontemporal_store(v, (u32x4*)(op + (h << 8) + (sl << 2)));
            }
        }
    }
}

// ---------------------------------------------------------------------------
extern "C" void kernel_launch(void* const* d_in, const int* in_sizes, int n_in,
                              void* d_out, int out_size, void* d_ws, size_t ws_size,
                              hipStream_t stream) {
    const float* x     = (const float*)d_in[0];
    const float* wq    = (const float*)d_in[1];
    const float* bq    = (const float*)d_in[2];
    const float* wk    = (const float*)d_in[3];
    const float* bk    = (const float*)d_in[4];
    const float* wv    = (const float*)d_in[5];
    const float* bv    = (const float*)d_in[6];
    const float* gamma = (const float*)d_in[7];
    float* out = (float*)d_out;

    // QKV fp16 workspace, padded rows (kept from R10).
    int rstride = 65536 + 64;
    size_t perMat = (size_t)512 * rstride;             // elements per matrix
    if (perMat * 3 * sizeof(_Float16) > ws_size) {
        rstride = 65536;
        perMat = (size_t)512 * rstride;
    }
    _Float16* Qh = (_Float16*)d_ws;
    _Float16* Kh = Qh + perMat;
    _Float16* Vh = Kh + perMat;

    proj_qkv_mfma<<<512, 256, 0, stream>>>(x, wq, bq, wk, bk, wv, bv, Qh, Kh, Vh, rstride);
    attn_rowsm<<<256, 1024, 0, stream>>>(Qh, Kh, Vh, gamma, out, rstride);
}

// Round 18
// 145.667 us; speedup vs baseline: 1.9062x; 1.9062x over previous
//
#include <hip/hip_runtime.h>

typedef _Float16 f16x8 __attribute__((ext_vector_type(8)));
typedef _Float16 f16x4 __attribute__((ext_vector_type(4)));
typedef float    f32x4 __attribute__((ext_vector_type(4)));
typedef unsigned int u32x4 __attribute__((ext_vector_type(4)));   // NT-store legal

// LDS-visibility-only barrier (no vmcnt drain): global stores issued before it
// keep draining in the background (used only in K1's round pipeline).
__device__ __forceinline__ void lds_barrier() {
    asm volatile("s_waitcnt lgkmcnt(0)" ::: "memory");
    __builtin_amdgcn_sched_barrier(0);
    __builtin_amdgcn_s_barrier();
    __builtin_amdgcn_sched_barrier(0);
}

// ===========================================================================
// CONSOLIDATED BEST (R13 configuration, measured 145.86 us):
//   K1 ~43us: MFMA -> OUT LDS transpose -> NT 1KB bulk stores (write path
//             2.05 -> ~5 TB/s; at its write roofline).
//   K2 ~103us: reg-staged depth-2 prefetch + __syncthreads + LDS-transpose
//             NT epilogue. 1 block/CU (256x256 acc = 64 AGPR + 160KB LDS)
//             forces serial phases; persistent/cross-slice variants spill at
//             the 128-reg/16-wave cap (R16/R17). Structural plateau.
// ===========================================================================
#define W_OFF   0      // 24576 B : w [192o][64c] fp16, row 128B, swz (orow&7)<<4
#define XA_OFF  24576  // 16384 B : x tile buf A fp16 [64c][128px], swz ((c>>3)&7)<<4
#define XB_OFF  40960  // 16384 B : x tile buf B
#define OUT_OFF 57344  // 24576 B : out [96oo][128px] fp16, swz (oo&7)<<4

__global__ __launch_bounds__(256, 2) void proj_qkv_mfma(
    const float* __restrict__ x,
    const float* __restrict__ wq, const float* __restrict__ bq,
    const float* __restrict__ wk, const float* __restrict__ bk,
    const float* __restrict__ wv, const float* __restrict__ bv,
    _Float16* __restrict__ Qh, _Float16* __restrict__ Kh, _Float16* __restrict__ Vh,
    const int rstride)
{
    __shared__ __align__(16) unsigned char lds[81920];

    const int tid  = threadIdx.x;
    const int lane = tid & 63;
    const int wid  = tid >> 6;
    const int q4   = lane >> 4;
    const int l15  = lane & 15;

    const int pg0  = blockIdx.x << 10;        // 1024 px per block
    const int bb   = pg0 >> 16;               // batch (1024 divides 65536)
    const int pix0 = pg0 & 65535;
    const float* xb = x + ((size_t)bb << 22); // bb*64*65536 (x stride fixed)

    const int sc = tid >> 5;                  // c row base for staging
    const int sslot = tid & 31;               // px = sslot*4

    // ---- bias preload ----
    float bld[12];
#pragma unroll
    for (int ot = 0; ot < 12; ++ot) {
        const int mat = ot >> 2;
        const float* bs = (mat == 0) ? bq : (mat == 1) ? bk : bv;
        bld[ot] = bs[((ot & 3) << 4) + l15];
    }

    // ---- stage ALL weights once: [192][64] f32 -> fp16 LDS ----
#pragma unroll
    for (int it = 0; it < 12; ++it) {
        const int idx  = (it << 8) + tid;
        const int orow = idx >> 4;
        const int s    = idx & 15;
        const int mat  = orow >> 6;
        const float* wsrc = (mat == 0) ? wq : (mat == 1) ? wk : wv;
        const f32x4 v = *(const f32x4*)(wsrc + ((orow & 63) << 6) + (s << 2));
        f16x4 h;
#pragma unroll
        for (int j = 0; j < 4; ++j) h[j] = (_Float16)v[j];
        const int a = ((orow << 7) + (s << 3)) ^ ((orow & 7) << 4);
        *(f16x4*)(lds + W_OFF + a) = h;
    }

    // ---- prologue: stage tile 0 into buf A ----
    {
        f32x4 xv[8];
#pragma unroll
        for (int it = 0; it < 8; ++it) {
            const int c = (it << 3) + sc;
            xv[it] = *(const f32x4*)(xb + ((size_t)c << 16) + pix0 + (sslot << 2));
        }
#pragma unroll
        for (int it = 0; it < 8; ++it) {
            const int c = (it << 3) + sc;
            f16x4 h;
#pragma unroll
            for (int j = 0; j < 4; ++j) h[j] = (_Float16)xv[it][j];
            const int a = ((c << 8) + (sslot << 3)) ^ (((c >> 3) & 7) << 4);
            *(f16x4*)(lds + XA_OFF + a) = h;
        }
    }
    __syncthreads();

    const int wpx = wid << 5;                  // wave px base (32 px/wave)

    for (int t = 0; t < 8; ++t) {
        const int bufo = (t & 1) ? XB_OFF : XA_OFF;
        const int nbufo = (t & 1) ? XA_OFF : XB_OFF;
        const int pixT = pix0 + (t << 7);

        // ---- issue tile t+1 loads NOW (in flight during compute) ----
        f32x4 xv[8];
        if (t < 7) {
            const int pixN = pixT + 128;
#pragma unroll
            for (int it = 0; it < 8; ++it) {
                const int c = (it << 3) + sc;
                xv[it] = *(const f32x4*)(xb + ((size_t)c << 16) + pixN + (sslot << 2));
            }
        }

        // ---- A fragments: lane l15 = px, k = c ----
        f16x8 af[2][2];
#pragma unroll
        for (int pt = 0; pt < 2; ++pt)
#pragma unroll
            for (int kc = 0; kc < 2; ++kc) {
                const int px = wpx + (pt << 4) + l15;
                f16x8 a;
#pragma unroll
                for (int j = 0; j < 8; ++j) {
                    const int c  = (kc << 5) + (q4 << 3) + j;
                    const int ad = ((c << 8) + (px << 1)) ^ (((c >> 3) & 7) << 4);
                    a[j] = *(const _Float16*)(lds + bufo + ad);
                }
                af[pt][kc] = a;
            }

        // ---- 2 rounds x 6 o-tiles: MFMA -> OUT LDS -> coalesced NT store ----
#pragma unroll
        for (int rd = 0; rd < 2; ++rd) {
            if (rd) lds_barrier();
#pragma unroll
            for (int ot6 = 0; ot6 < 6; ++ot6) {
                const int ot  = rd * 6 + ot6;
                const int row = (ot << 4) + l15;
                const int rsw = (row & 7) << 4;
                const f16x8 bf0 = *(const f16x8*)(lds + W_OFF + (((row << 7) + (q4 << 4)) ^ rsw));
                const f16x8 bf1 = *(const f16x8*)(lds + W_OFF + (((row << 7) + 64 + (q4 << 4)) ^ rsw));
                const int oo  = (ot6 << 4) + l15;
                const int osw = (oo & 7) << 4;
#pragma unroll
                for (int pt = 0; pt < 2; ++pt) {
                    f32x4 acc = { bld[ot], bld[ot], bld[ot], bld[ot] };
                    acc = __builtin_amdgcn_mfma_f32_16x16x32_f16(af[pt][0], bf0, acc, 0, 0, 0);
                    acc = __builtin_amdgcn_mfma_f32_16x16x32_f16(af[pt][1], bf1, acc, 0, 0, 0);
                    f16x4 h;
#pragma unroll
                    for (int r = 0; r < 4; ++r) h[r] = (_Float16)acc[r];
                    const int px = wpx + (pt << 4) + (q4 << 2);
                    *(f16x4*)(lds + OUT_OFF + (((oo << 8) + (px << 1)) ^ osw)) = h;
                }
            }
            lds_barrier();

            // bulk store: 4 rows x 256B contiguous per wave instr, NT flag
#pragma unroll
            for (int it = 0; it < 6; ++it) {
                const int idx = (it << 8) + tid;
                const int oo  = idx >> 4;          // 0..95
                const int sl  = idx & 15;          // 16B slot (8 px)
                const u32x4 vst = *(const u32x4*)(lds + OUT_OFF +
                    (((oo << 8) + (sl << 4)) ^ ((oo & 7) << 4)));
                const int ot  = rd * 6 + (oo >> 4);
                const int mat = ot >> 2;
                _Float16* ob = (mat == 0) ? Qh : (mat == 1) ? Kh : Vh;
                const int orow = ((ot & 3) << 4) + (oo & 15);
                u32x4* dst = (u32x4*)(ob + (size_t)((bb << 6) + orow) * rstride + pixT + (sl << 3));
                __builtin_nontemporal_store(vst, dst);
            }
        }

        // ---- cvt + ds_write tile t+1 into other x buffer ----
        if (t < 7) {
#pragma unroll
            for (int it = 0; it < 8; ++it) {
                const int c = (it << 3) + sc;
                f16x4 h;
#pragma unroll
                for (int j = 0; j < 4; ++j) h[j] = (_Float16)xv[it][j];
                const int a = ((c << 8) + (sslot << 3)) ^ (((c >> 3) & 7) << 4);
                *(f16x4*)(lds + nbufo + a) = h;
            }
        }
        lds_barrier();
    }
}

// ===========================================================================
// K2: fused attention per (b,c). R13 form (best measured ~103us co-run).
// ===========================================================================
#define P_OFF 0        // 131072 B : P fp16 [256][256] | out staging fp32 [128][256]
#define B_OFF 131072   //  16384 B : Q chunk | softmax partials | Vt chunk
#define K_OFF 147456   //  16384 B : K chunk

__global__ __launch_bounds__(1024, 4) void attn_rowsm(
    const _Float16* __restrict__ Qh, const _Float16* __restrict__ Kh,
    const _Float16* __restrict__ Vh, const float* __restrict__ gamma,
    float* __restrict__ out, const int rstride)
{
    __shared__ __align__(16) unsigned char lds[163840];

    const int tid  = threadIdx.x;
    const int lane = tid & 63;
    const int wid  = tid >> 6;
    const int wr   = wid >> 2;
    const int wc   = wid & 3;
    const int q4   = lane >> 4;
    const int l15  = lane & 15;
    const size_t qbase = (size_t)blockIdx.x * rstride;   // padded QKV slice

    const f32x4 fzero = {0.f, 0.f, 0.f, 0.f};
    f32x4 acc[4][4];
#pragma unroll
    for (int i = 0; i < 4; ++i)
#pragma unroll
        for (int j = 0; j < 4; ++j) acc[i][j] = fzero;

    // ---------------- phase 1: att = Q K^T (depth-2 prefetch) --------------
    const int sh = tid >> 2;                 // staging row 0..255
    const int ss = tid & 3;                  // 16B slot 0..3
    const int soff = ((sh << 6) + (ss << 4)) ^ ((sh & 7) << 4);
    const size_t sg = qbase + (size_t)sh * 256 + ss * 8;

    auto qk_compute = [&]() {
        f16x8 bf[4];
#pragma unroll
        for (int ni = 0; ni < 4; ++ni) {
            const int g = (wc << 6) + (ni << 4) + l15;
            bf[ni] = *(const f16x8*)(lds + K_OFF + (((g << 6) + (q4 << 4)) ^ ((g & 7) << 4)));
        }
#pragma unroll
        for (int mi = 0; mi < 4; ++mi) {
            const int h = (wr << 6) + (mi << 4) + l15;
            const f16x8 afr = *(const f16x8*)(lds + B_OFF + (((h << 6) + (q4 << 4)) ^ ((h & 7) << 4)));
#pragma unroll
            for (int ni = 0; ni < 4; ++ni)
                acc[mi][ni] = __builtin_amdgcn_mfma_f32_16x16x32_f16(afr, bf[ni], acc[mi][ni], 0, 0, 0);
        }
    };

    uint4 qdA = *(const uint4*)(Qh + sg);
    uint4 kdA = *(const uint4*)(Kh + sg);
    uint4 qdB = *(const uint4*)(Qh + sg + 32);
    uint4 kdB = *(const uint4*)(Kh + sg + 32);

    for (int kc = 0; kc < 256; kc += 64) {
        __syncthreads();
        *(uint4*)(lds + B_OFF + soff) = qdA;
        *(uint4*)(lds + K_OFF + soff) = kdA;
        if (kc < 192) {
            qdA = *(const uint4*)(Qh + sg + kc + 64);
            kdA = *(const uint4*)(Kh + sg + kc + 64);
        }
        __syncthreads();
        qk_compute();

        __syncthreads();
        *(uint4*)(lds + B_OFF + soff) = qdB;
        *(uint4*)(lds + K_OFF + soff) = kdB;
        if (kc < 192) {
            qdB = *(const uint4*)(Qh + sg + kc + 96);
            kdB = *(const uint4*)(Kh + sg + kc + 96);
        }
        __syncthreads();
        qk_compute();
    }

    // V chunks 0,1 prefetch: issue NOW so the softmax phase hides the latency
    const int gg = tid >> 5;                 // g within chunk 0..31
    const int wo = tid & 31;                 // w octet
    const size_t vg = qbase + (size_t)gg * 256 + wo * 8;
    uint4 vdA = *(const uint4*)(Vh + vg);
    uint4 vdB = *(const uint4*)(Vh + vg + 32 * 256);

    // ---------------- phase 2: diag add + softmax over h ----------------
    const float g_sig = 1.0f / (1.0f + __expf(-gamma[0]));
    if (wr == wc) {                          // diagonal tiles: h==g
        const int rn = l15 - (q4 << 2);
        if (rn >= 0 && rn < 4) {
#pragma unroll
            for (int mi = 0; mi < 4; ++mi) acc[mi][mi][rn] += g_sig;
        }
    }

    float* red = (float*)(lds + B_OFF);      // [4][256] partials
    float cmx[4], cinv[4];

    __syncthreads();                         // phase-1 LDS now dead
#pragma unroll
    for (int ni = 0; ni < 4; ++ni) {
        float m = -3.0e38f;
#pragma unroll
        for (int mi = 0; mi < 4; ++mi)
#pragma unroll
            for (int r = 0; r < 4; ++r) m = fmaxf(m, acc[mi][ni][r]);
        m = fmaxf(m, __shfl_xor(m, 16));
        m = fmaxf(m, __shfl_xor(m, 32));
        cmx[ni] = m;
        if (q4 == 0) red[wr * 256 + (wc << 6) + (ni << 4) + l15] = m;
    }
    __syncthreads();
#pragma unroll
    for (int ni = 0; ni < 4; ++ni) {
        const int col = (wc << 6) + (ni << 4) + l15;
        float m = red[col];
        m = fmaxf(m, red[256 + col]);
        m = fmaxf(m, red[512 + col]);
        m = fmaxf(m, red[768 + col]);
        cmx[ni] = m;
    }
    __syncthreads();                         // maxes consumed; reuse red for sums
#pragma unroll
    for (int ni = 0; ni < 4; ++ni) {
        float s = 0.f;
#pragma unroll
        for (int mi = 0; mi < 4; ++mi)
#pragma unroll
            for (int r = 0; r < 4; ++r) {
                const float e = __expf(acc[mi][ni][r] - cmx[ni]);
                acc[mi][ni][r] = e;
                s += e;
            }
        s += __shfl_xor(s, 16);
        s += __shfl_xor(s, 32);
        if (q4 == 0) red[wr * 256 + (wc << 6) + (ni << 4) + l15] = s;
    }
    __syncthreads();
#pragma unroll
    for (int ni = 0; ni < 4; ++ni) {
        const int col = (wc << 6) + (ni << 4) + l15;
        cinv[ni] = 1.0f / (red[col] + red[256 + col] + red[512 + col] + red[768 + col]);
    }

    // write normalized P to LDS (fp16, swizzled [256][256])
#pragma unroll
    for (int mi = 0; mi < 4; ++mi) {
        const int hbase = (wr << 6) + (mi << 4) + (q4 << 2);
#pragma unroll
        for (int r = 0; r < 4; ++r) {
            const int h  = hbase + r;
            const int hb = h << 9;           // h*512 bytes
            const int sw = (h & 7) << 4;
#pragma unroll
            for (int ni = 0; ni < 4; ++ni) {
                const int g = (wc << 6) + (ni << 4) + l15;
                *(_Float16*)(lds + P_OFF + ((hb + (g << 1)) ^ sw)) =
                    (_Float16)(acc[mi][ni][r] * cinv[ni]);
            }
        }
    }

    // ---------------- phase 3: out = P V (depth-2 prefetch) ----------------
#pragma unroll
    for (int i = 0; i < 4; ++i)
#pragma unroll
        for (int j = 0; j < 4; ++j) acc[i][j] = fzero;

    auto v_write = [&](const uint4& vd) {
        const _Float16* ve = (const _Float16*)&vd;
#pragma unroll
        for (int j = 0; j < 8; ++j) {
            const int w  = (wo << 3) + j;
            const int fw = ((w & 7) ^ ((w >> 3) & 7)) << 4;
            *(_Float16*)(lds + B_OFF + (((w << 6) + (gg << 1)) ^ fw)) = ve[j];
        }
    };
    auto pv_compute = [&](int gc) {
        f16x8 bf[4];
#pragma unroll
        for (int ni = 0; ni < 4; ++ni) {
            const int w  = (wc << 6) + (ni << 4) + l15;
            const int fw = ((w & 7) ^ ((w >> 3) & 7)) << 4;
            bf[ni] = *(const f16x8*)(lds + B_OFF + (((w << 6) + (q4 << 4)) ^ fw));
        }
#pragma unroll
        for (int mi = 0; mi < 4; ++mi) {
            const int h = (wr << 6) + (mi << 4) + l15;
            const f16x8 afr = *(const f16x8*)(lds + P_OFF +
                (((h << 9) + ((gc + (q4 << 3)) << 1)) ^ ((h & 7) << 4)));
#pragma unroll
            for (int ni = 0; ni < 4; ++ni)
                acc[mi][ni] = __builtin_amdgcn_mfma_f32_16x16x32_f16(afr, bf[ni], acc[mi][ni], 0, 0, 0);
        }
    };

    for (int gc = 0; gc < 256; gc += 64) {
        __syncthreads();                     // P written / prior Vt reads done
        v_write(vdA);
        if (gc < 192) vdA = *(const uint4*)(Vh + vg + (size_t)(gc + 64) * 256);
        __syncthreads();
        pv_compute(gc);

        __syncthreads();
        v_write(vdB);
        if (gc < 192) vdB = *(const uint4*)(Vh + vg + (size_t)(gc + 96) * 256);
        __syncthreads();
        pv_compute(gc + 32);
    }

    // ---- epilogue: LDS-transpose + NT bulk store (2 passes x 128 rows) ----
    float* op = out + ((size_t)blockIdx.x << 16);
#pragma unroll
    for (int pass = 0; pass < 2; ++pass) {
        __syncthreads();                     // P reads / prior bulk reads done
#pragma unroll
        for (int mi2 = 0; mi2 < 2; ++mi2) {
            const int mi = pass * 2 + mi2;
#pragma unroll
            for (int r = 0; r < 4; ++r) {
                const int lr = (wr << 5) + (mi2 << 4) + (q4 << 2) + r;  // 0..127
                const int sw = (lr & 7) << 4;
#pragma unroll
                for (int ni = 0; ni < 4; ++ni) {
                    const int w = (wc << 6) + (ni << 4) + l15;
                    *(float*)(lds + P_OFF + (((lr << 10) + (w << 2)) ^ sw)) =
                        acc[mi][ni][r];
                }
            }
        }
        __syncthreads();                     // staging visible
#pragma unroll
        for (int it = 0; it < 8; ++it) {
            const int idx = (it << 10) + tid;
            const int row = idx >> 6;        // 0..127 (uniform per wave)
            const int sl  = idx & 63;        // 16B slot = lane
            const u32x4 v = *(const u32x4*)(lds + P_OFF +
                (((row << 10) + (sl << 4)) ^ ((row & 7) << 4)));
            const int h = ((row >> 5) << 6) + (pass << 5) + (row & 31);
            u32x4* dst = (u32x4*)(op + (h << 8) + (sl << 2));
            __builtin_nontemporal_store(v, dst);
        }
    }
}

// ---------------------------------------------------------------------------
extern "C" void kernel_launch(void* const* d_in, const int* in_sizes, int n_in,
                              void* d_out, int out_size, void* d_ws, size_t ws_size,
                              hipStream_t stream) {
    const float* x     = (const float*)d_in[0];
    const float* wq    = (const float*)d_in[1];
    const float* bq    = (const float*)d_in[2];
    const float* wk    = (const float*)d_in[3];
    const float* bk    = (const float*)d_in[4];
    const float* wv    = (const float*)d_in[5];
    const float* bv    = (const float*)d_in[6];
    const float* gamma = (const float*)d_in[7];
    float* out = (float*)d_out;

    // QKV fp16 workspace, padded rows.
    int rstride = 65536 + 64;
    size_t perMat = (size_t)512 * rstride;             // elements per matrix
    if (perMat * 3 * sizeof(_Float16) > ws_size) {
        rstride = 65536;
        perMat = (size_t)512 * rstride;
    }
    _Float16* Qh = (_Float16*)d_ws;
    _Float16* Kh = Qh + perMat;
    _Float16* Vh = Kh + perMat;

    proj_qkv_mfma<<<512, 256, 0, stream>>>(x, wq, bq, wk, bk, wv, bv, Qh, Kh, Vh, rstride);
    attn_rowsm<<<512, 1024, 0, stream>>>(Qh, Kh, Vh, gamma, out, rstride);
}